// Round 10
// baseline (282.339 us; speedup 1.0000x reference)
//
#include <hip/hip_runtime.h>

typedef float f32x4 __attribute__((ext_vector_type(4)));
typedef __bf16 bf16x8 __attribute__((ext_vector_type(8)));
typedef int i32x4 __attribute__((ext_vector_type(4)));

__device__ __forceinline__ unsigned short f2bf(float f) {
    union { float f; unsigned u; } v; v.f = f;
    unsigned r = v.u + 0x7fffu + ((v.u >> 16) & 1u);
    return (unsigned short)(r >> 16);
}

#define AS1 __attribute__((address_space(1)))
#define AS3 __attribute__((address_space(3)))
// async 16B/lane global->LDS
__device__ __forceinline__ void async16(const void* g, void* l) {
    __builtin_amdgcn_global_load_lds((AS1 void*)g, (AS3 void*)l, 16, 0, 0);
}

// CK-style barrier: orders LDS only (lgkmcnt), leaves global loads (vmcnt) in flight.
__device__ __forceinline__ void sync_lds() {
    asm volatile("s_waitcnt lgkmcnt(0)\n\ts_barrier" ::: "memory");
}

// XOR swizzle for 32-col (4-group) rows
#define SWZ4(r) ((((r) & 3) ^ (((r) >> 2) & 3)))

// ---------------- weight transpose + bf16 convert: W[K][N] -> Wt[N][K] ----------------
__global__ void transpose_cvt(const float* __restrict__ W, unsigned short* __restrict__ Wt,
                              int K, int N) {
    __shared__ float tile[32][33];
    int n0 = blockIdx.x * 32, k0 = blockIdx.y * 32;
    int tx = threadIdx.x, ty = threadIdx.y;
#pragma unroll
    for (int i = 0; i < 32; i += 8)
        tile[ty + i][tx] = W[(size_t)(k0 + ty + i) * N + n0 + tx];
    __syncthreads();
#pragma unroll
    for (int i = 0; i < 32; i += 8)
        Wt[(size_t)(n0 + ty + i) * K + k0 + tx] = f2bf(tile[tx][ty + i]);
}

// ---------------- LayerNorm (ddof=1, /(std+eps)), fp32 in -> bf16 out ----------------
__global__ __launch_bounds__(256) void ln_kernel(const float* __restrict__ x,
                                                 unsigned short* __restrict__ t,
                                                 const float* __restrict__ alpha,
                                                 const float* __restrict__ bias) {
    const int row = blockIdx.x;
    const float* xr = x + (size_t)row * 768;
    float v[3], sum = 0.f, ss = 0.f;
#pragma unroll
    for (int i = 0; i < 3; i++) {
        v[i] = xr[threadIdx.x + 256 * i];
        sum += v[i]; ss += v[i] * v[i];
    }
#pragma unroll
    for (int off = 32; off; off >>= 1) {
        sum += __shfl_down(sum, off);
        ss  += __shfl_down(ss, off);
    }
    __shared__ float s1[4], s2[4];
    int wid = threadIdx.x >> 6, lane = threadIdx.x & 63;
    if (lane == 0) { s1[wid] = sum; s2[wid] = ss; }
    __syncthreads();
    if (threadIdx.x == 0) {
        float a = 0.f, b = 0.f;
#pragma unroll
        for (int i = 0; i < 4; i++) { a += s1[i]; b += s2[i]; }
        s1[0] = a; s2[0] = b;
    }
    __syncthreads();
    sum = s1[0]; ss = s2[0];
    float mean = sum * (1.f / 768.f);
    float var = (ss - sum * mean) * (1.f / 767.f);   // unbiased (ddof=1)
    float sc = alpha[0] / (sqrtf(fmaxf(var, 0.f)) + 1e-6f);
    float bs = bias[0];
#pragma unroll
    for (int i = 0; i < 3; i++)
        t[(size_t)row * 768 + threadIdx.x + 256 * i] = f2bf(sc * (v[i] - mean) + bs);
}

// ---------------- GEMM 128x128, register-prefetch pipelined, BK=32 --------------------
// MODE 0: out bf16 = v              MODE 1: out bf16 = relu(v + bias[col])
// MODE 2: out f32 = v + res         MODE 3: out f32 = v + bias[col] + res
template <int MODE>
__global__ __launch_bounds__(256, 3) void gemm_bt(
    const unsigned short* __restrict__ A, const unsigned short* __restrict__ Bt,
    int M, int N, int K, const float* __restrict__ bias,
    const float* __restrict__ res, void* __restrict__ outp) {
    __shared__ __align__(16) unsigned short As[2][128 * 32];
    __shared__ __align__(16) unsigned short Bs[2][128 * 32];
    const int tid = threadIdx.x;
    const int lane = tid & 63, w = tid >> 6;
    const int wm = w & 1, wn = w >> 1;
    const int m0 = blockIdx.y * 128, n0 = blockIdx.x * 128;
    const int quad = lane >> 4, l16 = lane & 15;

    const int r0 = tid >> 2, g0 = tid & 3;           // rows 0..63
    const int r1 = r0 + 64, g1 = g0;                 // rows 64..127
    const unsigned short* gA0 = A  + (size_t)(m0 + r0) * K + g0 * 8;
    const unsigned short* gA1 = A  + (size_t)(m0 + r1) * K + g1 * 8;
    const unsigned short* gB0 = Bt + (size_t)(n0 + r0) * K + g0 * 8;
    const unsigned short* gB1 = Bt + (size_t)(n0 + r1) * K + g1 * 8;
    const int wA0 = r0 * 32 + ((g0 ^ SWZ4(r0)) * 8);
    const int wA1 = r1 * 32 + ((g1 ^ SWZ4(r1)) * 8);

    f32x4 acc[4][4];
    const f32x4 z = {0.f, 0.f, 0.f, 0.f};
#pragma unroll
    for (int mt = 0; mt < 4; mt++)
#pragma unroll
        for (int nt = 0; nt < 4; nt++) acc[mt][nt] = z;

    bf16x8 ra0 = *(const bf16x8*)gA0, ra1 = *(const bf16x8*)gA1;
    bf16x8 rb0 = *(const bf16x8*)gB0, rb1 = *(const bf16x8*)gB1;
    gA0 += 32; gA1 += 32; gB0 += 32; gB1 += 32;

    const int nK = K >> 5;
    for (int kt = 0; kt < nK; ++kt) {
        unsigned short* Ac = As[kt & 1];
        unsigned short* Bc = Bs[kt & 1];
        *(bf16x8*)&Ac[wA0] = ra0; *(bf16x8*)&Ac[wA1] = ra1;
        *(bf16x8*)&Bc[wA0] = rb0; *(bf16x8*)&Bc[wA1] = rb1;
        if (kt + 1 < nK) {
            ra0 = *(const bf16x8*)gA0; ra1 = *(const bf16x8*)gA1;
            rb0 = *(const bf16x8*)gB0; rb1 = *(const bf16x8*)gB1;
            gA0 += 32; gA1 += 32; gB0 += 32; gB1 += 32;
        }
        sync_lds();
        bf16x8 af[4], bf[4];
#pragma unroll
        for (int mt = 0; mt < 4; mt++) {
            int r = 64 * wm + 16 * mt + l16;
            af[mt] = *(const bf16x8*)&Ac[r * 32 + ((quad ^ SWZ4(r)) * 8)];
        }
#pragma unroll
        for (int nt = 0; nt < 4; nt++) {
            int r = 64 * wn + 16 * nt + l16;
            bf[nt] = *(const bf16x8*)&Bc[r * 32 + ((quad ^ SWZ4(r)) * 8)];
        }
#pragma unroll
        for (int mt = 0; mt < 4; mt++)
#pragma unroll
            for (int nt = 0; nt < 4; nt++)
                acc[mt][nt] = __builtin_amdgcn_mfma_f32_16x16x32_bf16(af[mt], bf[nt], acc[mt][nt], 0, 0, 0);
    }

#pragma unroll
    for (int mt = 0; mt < 4; mt++) {
#pragma unroll
        for (int nt = 0; nt < 4; nt++) {
            const int col = n0 + 64 * wn + 16 * nt + l16;
            float bv = 0.f;
            if (MODE == 1 || MODE == 3) bv = bias[col];
#pragma unroll
            for (int r = 0; r < 4; r++) {
                const int row = m0 + 64 * wm + 16 * mt + quad * 4 + r;
                const size_t idx = (size_t)row * N + col;
                const float v = acc[mt][nt][r];
                if (MODE == 0) ((unsigned short*)outp)[idx] = f2bf(v);
                else if (MODE == 1) ((unsigned short*)outp)[idx] = f2bf(fmaxf(v + bv, 0.f));
                else if (MODE == 2) ((float*)outp)[idx] = v + res[idx];
                else ((float*)outp)[idx] = v + bv + res[idx];
            }
        }
    }
}

// ---------------- GEMM 64x64, register-prefetch pipelined, BK=64 ----------------------
template <int MODE>
__global__ __launch_bounds__(256, 3) void gemm64_bt(
    const unsigned short* __restrict__ A, const unsigned short* __restrict__ Bt,
    int M, int N, int K, const float* __restrict__ bias,
    const float* __restrict__ res, void* __restrict__ outp) {
    __shared__ __align__(16) unsigned short As[2][64 * 64];
    __shared__ __align__(16) unsigned short Bs[2][64 * 64];
    const int tid = threadIdx.x;
    const int lane = tid & 63, w = tid >> 6;
    const int m0 = blockIdx.y * 64, n0 = blockIdx.x * 64;
    const int quad = lane >> 4, l16 = lane & 15;

    const int r0 = tid >> 3, g0 = tid & 7;           // rows 0..31
    const int r1 = r0 + 32, g1 = g0;                 // rows 32..63
    const unsigned short* gA0 = A  + (size_t)(m0 + r0) * K + g0 * 8;
    const unsigned short* gA1 = A  + (size_t)(m0 + r1) * K + g1 * 8;
    const unsigned short* gB0 = Bt + (size_t)(n0 + r0) * K + g0 * 8;
    const unsigned short* gB1 = Bt + (size_t)(n0 + r1) * K + g1 * 8;
    const int wA0 = r0 * 64 + ((g0 ^ (r0 & 7)) * 8);
    const int wA1 = r1 * 64 + ((g1 ^ (r1 & 7)) * 8);

    f32x4 acc[4];
    const f32x4 z = {0.f, 0.f, 0.f, 0.f};
#pragma unroll
    for (int nt = 0; nt < 4; nt++) acc[nt] = z;

    bf16x8 ra0 = *(const bf16x8*)gA0, ra1 = *(const bf16x8*)gA1;
    bf16x8 rb0 = *(const bf16x8*)gB0, rb1 = *(const bf16x8*)gB1;
    gA0 += 64; gA1 += 64; gB0 += 64; gB1 += 64;

    const int nK = K >> 6;
    for (int kt = 0; kt < nK; ++kt) {
        unsigned short* Ac = As[kt & 1];
        unsigned short* Bc = Bs[kt & 1];
        *(bf16x8*)&Ac[wA0] = ra0; *(bf16x8*)&Ac[wA1] = ra1;
        *(bf16x8*)&Bc[wA0] = rb0; *(bf16x8*)&Bc[wA1] = rb1;
        if (kt + 1 < nK) {
            ra0 = *(const bf16x8*)gA0; ra1 = *(const bf16x8*)gA1;
            rb0 = *(const bf16x8*)gB0; rb1 = *(const bf16x8*)gB1;
            gA0 += 64; gA1 += 64; gB0 += 64; gB1 += 64;
        }
        sync_lds();
        const int ra = 16 * w + l16;
        bf16x8 af0 = *(const bf16x8*)&Ac[ra * 64 + (((0 + quad) ^ (ra & 7)) * 8)];
        bf16x8 af1 = *(const bf16x8*)&Ac[ra * 64 + (((4 + quad) ^ (ra & 7)) * 8)];
#pragma unroll
        for (int nt = 0; nt < 4; nt++) {
            int rb = 16 * nt + l16;
            bf16x8 bf0 = *(const bf16x8*)&Bc[rb * 64 + (((0 + quad) ^ (rb & 7)) * 8)];
            bf16x8 bf1 = *(const bf16x8*)&Bc[rb * 64 + (((4 + quad) ^ (rb & 7)) * 8)];
            acc[nt] = __builtin_amdgcn_mfma_f32_16x16x32_bf16(af0, bf0, acc[nt], 0, 0, 0);
            acc[nt] = __builtin_amdgcn_mfma_f32_16x16x32_bf16(af1, bf1, acc[nt], 0, 0, 0);
        }
    }

#pragma unroll
    for (int nt = 0; nt < 4; nt++) {
        const int col = n0 + 16 * nt + l16;
        float bv = 0.f;
        if (MODE == 1 || MODE == 3) bv = bias[col];
#pragma unroll
        for (int rr = 0; rr < 4; rr++) {
            const int row = m0 + 16 * w + quad * 4 + rr;
            const size_t idx = (size_t)row * N + col;
            const float v = acc[nt][rr];
            if (MODE == 0) ((unsigned short*)outp)[idx] = f2bf(v);
            else if (MODE == 1) ((unsigned short*)outp)[idx] = f2bf(fmaxf(v + bv, 0.f));
            else if (MODE == 2) ((float*)outp)[idx] = v + res[idx];
            else ((float*)outp)[idx] = v + bv + res[idx];
        }
    }
}

// ---------------- V transpose: qkv[.,1536+h*64+dd] -> vt[bh][dd][S] ----------------
__global__ void v_transpose(const unsigned short* __restrict__ qkvc,
                            unsigned short* __restrict__ vt) {
    __shared__ unsigned short t[64][65];
    const int bh = blockIdx.y, b = bh / 12, h = bh % 12;
    const int s0 = blockIdx.x * 64;
    const int tx = threadIdx.x, ty = threadIdx.y;   // 64 x 4
#pragma unroll
    for (int i = 0; i < 64; i += 4)
        t[ty + i][tx] = qkvc[(size_t)(b * 2048 + s0 + ty + i) * 2304 + 1536 + h * 64 + tx];
    __syncthreads();
#pragma unroll
    for (int i = 0; i < 64; i += 4)
        vt[((size_t)bh * 64 + ty + i) * 2048 + s0 + tx] = t[tx][ty + i];
}

// ---------------- flash attention v8: 2x2 hybrid split + S^T (vectorized P write) -----
// v7 skeleton, but QK^T computed TRANSPOSED: mfma(A=K-frag, B=Q-frag) -> D = K Q^T =
// S^T, whose C-layout gives each lane q=l16 fixed, k=quad*4+r consecutive -> the 4
// exp'd P values are 8 CONTIGUOUS bytes in row-major Ps: one ds_write_b64 per 16x16
// tile (32 ds_write_b16 -> 8 ds_write_b64 per wave-iter). A/B frag register layouts
// are bit-identical, so K/Q LDS reads and the PV loop are unchanged. Mask is k-indexed
// per lane now: one broadcast int4 read per nt; masked P == bf16(exp(1e-9)) == 1.0.
__global__ __launch_bounds__(256, 3) void flash_attn(
    const unsigned short* __restrict__ qkvc,   // [4096][2304] fused q|k|v
    const unsigned short* __restrict__ vt,     // [24][64][2048]
    const int* __restrict__ mask,              // [2][2048]
    unsigned short* __restrict__ attno) {      // [4096][768]
    const int bh = blockIdx.y, b = bh / 12, h = bh % 12;
    const int s0 = blockIdx.x * 64;
    __shared__ __align__(16) unsigned short UQP[4 * 32 * 72];  // Qs pre-loop; Ps[w][32][72]
    __shared__ __align__(16) unsigned short Ks[128 * 64];      // fp32 Osc[64][64] in epilogue
    __shared__ __align__(16) unsigned short Vs[64 * 128];      // fp32 Lsc[64] in epilogue
    __shared__ int Ms[128];
    const int tid = threadIdx.x, lane = tid & 63, w = tid >> 6;
    const int quad = lane >> 4, l16 = lane & 15;
    const int wq = w & 1, wk = w >> 1;

    // stage Q tile [64 rows][64 cols] (swizzle g^(r&7)) via async16, once
    {
        int sl0 = (2 * w) * 64 + lane;
        int r0 = sl0 >> 3, g0 = sl0 & 7;
        int sl1 = sl0 + 64;
        int r1 = sl1 >> 3, g1 = sl1 & 7;
        async16(qkvc + (size_t)(b * 2048 + s0 + r0) * 2304 + h * 64 + ((g0 ^ (r0 & 7)) * 8),
                UQP + (2 * w) * 512);
        async16(qkvc + (size_t)(b * 2048 + s0 + r1) * 2304 + h * 64 + ((g1 ^ (r1 & 7)) * 8),
                UQP + (2 * w + 1) * 512);
    }
    __syncthreads();
    // Q frags for this wave's 32 q-rows (2 x 16-row blocks, K=64 dims); used as
    // B-operand below (bit-identical layout: 8 consecutive k-dim elems per lane)
    bf16x8 aQ[2][2];
#pragma unroll
    for (int mt = 0; mt < 2; mt++) {
        int r = wq * 32 + mt * 16 + l16;
#pragma unroll
        for (int kk = 0; kk < 2; kk++)
            aQ[mt][kk] = *(const bf16x8*)&UQP[r * 64 + (((kk * 4 + quad) ^ (r & 7)) * 8)];
    }
    __syncthreads();   // all waves done reading Q before Ps overwrites the region
    __bf16* Ps = (__bf16*)UQP + w * (32 * 72);   // wave-local [32 q][stride 72]

    f32x4 Oacc[2][4], Lacc[2];
    const f32x4 z = {0.f, 0.f, 0.f, 0.f};
#pragma unroll
    for (int mt = 0; mt < 2; mt++) {
        Lacc[mt] = z;
#pragma unroll
        for (int nt = 0; nt < 4; nt++) Oacc[mt][nt] = z;
    }
    bf16x8 ones;
#pragma unroll
    for (int i = 0; i < 8; i++) ones[i] = (__bf16)1.0f;

    const unsigned short* kbase = qkvc + 768;
    const unsigned short* vbase = vt + (size_t)bh * 64 * 2048;
    const float SCL = 0.125f * 1.44269504088896340736f;   // 1/sqrt(64) * log2(e)

    for (int j = 0; j < 16; j++) {
        const int k0 = j * 128;
        __syncthreads();
        // stage K tile [128][64] (swizzle g^(r&7)) and V^T tile [64][128] (g^(r&15))
#pragma unroll
        for (int c = 0; c < 4; c++) {
            int sl = (4 * w + c) * 64 + lane;
            int r = sl >> 3, g = sl & 7;
            async16(kbase + (size_t)(b * 2048 + k0 + r) * 2304 + h * 64 + ((g ^ (r & 7)) * 8),
                    Ks + (4 * w + c) * 512);
        }
#pragma unroll
        for (int c = 0; c < 4; c++) {
            int sl = (4 * w + c) * 64 + lane;
            int r = sl >> 4, g = sl & 15;
            async16(vbase + (size_t)r * 2048 + k0 + ((g ^ (r & 15)) * 8),
                    Vs + (4 * w + c) * 512);
        }
        if (tid < 128) Ms[tid] = mask[b * 2048 + k0 + tid];
        __syncthreads();

        // S^T[64 k][32 q] for this wave's quadrant: mfma(A=K, B=Q). C-layout: lane
        // l16 = q, rows quad*4+r = 4 consecutive k -> one b64 P-write per tile.
#pragma unroll
        for (int nt = 0; nt < 4; nt++) {
            const int rr = wk * 64 + nt * 16 + l16;
            bf16x8 bk0 = *(const bf16x8*)&Ks[rr * 64 + (((0 + quad) ^ (rr & 7)) * 8)];
            bf16x8 bk1 = *(const bf16x8*)&Ks[rr * 64 + (((4 + quad) ^ (rr & 7)) * 8)];
            const i32x4 mk4 = *(const i32x4*)&Ms[wk * 64 + nt * 16 + quad * 4];
#pragma unroll
            for (int mt = 0; mt < 2; mt++) {
                f32x4 t0 = __builtin_amdgcn_mfma_f32_16x16x32_bf16(bk0, aQ[mt][0], z, 0, 0, 0);
                f32x4 sc = __builtin_amdgcn_mfma_f32_16x16x32_bf16(bk1, aQ[mt][1], t0, 0, 0, 0);
                union { unsigned long long u64; unsigned short s[4]; } pk;
#pragma unroll
                for (int r = 0; r < 4; r++) {
                    float p = __builtin_amdgcn_exp2f(sc[r] * SCL);
                    pk.s[r] = mk4[r] ? f2bf(p) : (unsigned short)0x3F80;  // bf16 1.0
                }
                *(unsigned long long*)&Ps[(mt * 16 + l16) * 72 + nt * 16 + quad * 4] = pk.u64;
            }
        }

        // O_w += P_w V[64k chunk] ; L_w += P_w 1
#pragma unroll
        for (int kt2 = 0; kt2 < 2; kt2++) {
#pragma unroll
            for (int mt = 0; mt < 2; mt++) {
                bf16x8 aP = *(const bf16x8*)&Ps[(mt * 16 + l16) * 72 + kt2 * 32 + quad * 8];
                Lacc[mt] = __builtin_amdgcn_mfma_f32_16x16x32_bf16(aP, ones, Lacc[mt], 0, 0, 0);
#pragma unroll
                for (int nt = 0; nt < 4; nt++) {
                    const int rr = nt * 16 + l16;
                    bf16x8 bv = *(const bf16x8*)&Vs[rr * 128 +
                                (((wk * 8 + kt2 * 4 + quad) ^ (rr & 15)) * 8)];
                    Oacc[mt][nt] = __builtin_amdgcn_mfma_f32_16x16x32_bf16(aP, bv, Oacc[mt][nt], 0, 0, 0);
                }
            }
        }
    }

    // ---- pair-merge: wk=1 publishes partials, wk=0 adds + stores ----
    __syncthreads();
    float* Osc = (float*)Ks;   // [64 q][64 d] fp32 = 16KB
    float* Lsc = (float*)Vs;   // [64 q] fp32
    if (wk == 1) {
#pragma unroll
        for (int mt = 0; mt < 2; mt++) {
            if (l16 == 0)
#pragma unroll
                for (int r = 0; r < 4; r++)
                    Lsc[wq * 32 + mt * 16 + quad * 4 + r] = Lacc[mt][r];
#pragma unroll
            for (int nt = 0; nt < 4; nt++)
#pragma unroll
                for (int r = 0; r < 4; r++)
                    Osc[(size_t)(wq * 32 + mt * 16 + quad * 4 + r) * 64 + nt * 16 + l16] =
                        Oacc[mt][nt][r];
        }
    }
    __syncthreads();
    if (wk == 0) {
#pragma unroll
        for (int mt = 0; mt < 2; mt++) {
#pragma unroll
            for (int r = 0; r < 4; r++) {
                const int ql = wq * 32 + mt * 16 + quad * 4 + r;
                const float L = Lacc[mt][r] + Lsc[ql];
                const float inv = 1.0f / L;
                const int row = s0 + ql;
#pragma unroll
                for (int nt = 0; nt < 4; nt++) {
                    const float s = Oacc[mt][nt][r] + Osc[(size_t)ql * 64 + nt * 16 + l16];
                    attno[(size_t)(b * 2048 + row) * 768 + h * 64 + nt * 16 + l16] =
                        f2bf(s * inv);
                }
            }
        }
    }
}

// =====================================================================================
extern "C" void kernel_launch(void* const* d_in, const int* in_sizes, int n_in,
                              void* d_out, int out_size, void* d_ws, size_t ws_size,
                              hipStream_t stream) {
    const float* x    = (const float*)d_in[0];
    const int*   mask = (const int*)d_in[1];
    const float* wq   = (const float*)d_in[2];
    const float* wk   = (const float*)d_in[3];
    const float* wv   = (const float*)d_in[4];
    const float* wo   = (const float*)d_in[5];
    const float* w1   = (const float*)d_in[6];
    const float* b1   = (const float*)d_in[7];
    const float* w2   = (const float*)d_in[8];
    const float* b2   = (const float*)d_in[9];
    const float* ln1a = (const float*)d_in[10];
    const float* ln1b = (const float*)d_in[11];
    const float* ln2a = (const float*)d_in[12];
    const float* ln2b = (const float*)d_in[13];

    char* p = (char*)d_ws;
    auto carve = [&](size_t bytes) {
        char* q = p;
        p += (bytes + 255) & ~(size_t)255;
        return q;
    };
    unsigned short* wTqkv = (unsigned short*)carve((size_t)2304 * 768 * 2);
    unsigned short* wTo   = (unsigned short*)carve((size_t)768 * 768 * 2);
    unsigned short* wT1   = (unsigned short*)carve((size_t)3072 * 768 * 2);
    unsigned short* wT2   = (unsigned short*)carve((size_t)768 * 3072 * 2);
    unsigned short* vtb   = (unsigned short*)carve((size_t)24 * 64 * 2048 * 2);
    float*          x1    = (float*)carve((size_t)4096 * 768 * 4);
    char* unionA = carve((size_t)4096 * 768 * 2 + (size_t)4096 * 2304 * 2);
    unsigned short* t1   = (unsigned short*)unionA;
    unsigned short* qkvc = (unsigned short*)(unionA + (size_t)4096 * 768 * 2);
    unsigned short* ffnh = (unsigned short*)unionA;
    unsigned short* attno = (unsigned short*)carve((size_t)4096 * 768 * 2);
    unsigned short* t2 = attno;

    dim3 tb(32, 8);
    transpose_cvt<<<dim3(24, 24), tb, 0, stream>>>(wq, wTqkv, 768, 768);
    transpose_cvt<<<dim3(24, 24), tb, 0, stream>>>(wk, wTqkv + (size_t)768 * 768, 768, 768);
    transpose_cvt<<<dim3(24, 24), tb, 0, stream>>>(wv, wTqkv + (size_t)1536 * 768, 768, 768);
    transpose_cvt<<<dim3(24, 24), tb, 0, stream>>>(wo, wTo, 768, 768);
    transpose_cvt<<<dim3(96, 24), tb, 0, stream>>>(w1, wT1, 768, 3072);
    transpose_cvt<<<dim3(24, 96), tb, 0, stream>>>(w2, wT2, 3072, 768);

    ln_kernel<<<4096, 256, 0, stream>>>(x, t1, ln1a, ln1b);
    gemm_bt<0><<<dim3(18, 32), 256, 0, stream>>>(t1, wTqkv, 4096, 2304, 768,
                                                 nullptr, nullptr, qkvc);
    v_transpose<<<dim3(32, 24), dim3(64, 4), 0, stream>>>(qkvc, vtb);
    flash_attn<<<dim3(32, 24), 256, 0, stream>>>(qkvc, vtb, mask, attno);
    gemm64_bt<2><<<dim3(12, 64), 256, 0, stream>>>(attno, wTo, 4096, 768, 768,
                                                   nullptr, x, x1);
    ln_kernel<<<4096, 256, 0, stream>>>(x1, t2, ln2a, ln2b);
    gemm_bt<1><<<dim3(24, 32), 256, 0, stream>>>(t2, wT1, 4096, 3072, 768,
                                                 b1, nullptr, ffnh);
    gemm64_bt<3><<<dim3(12, 64), 256, 0, stream>>>(ffnh, wT2, 4096, 768, 3072,
                                                   b2, x1, (float*)d_out);
}

// Round 11
// 274.728 us; speedup vs baseline: 1.0277x; 1.0277x over previous
//
#include <hip/hip_runtime.h>

typedef float f32x4 __attribute__((ext_vector_type(4)));
typedef __bf16 bf16x8 __attribute__((ext_vector_type(8)));
typedef int i32x4 __attribute__((ext_vector_type(4)));

__device__ __forceinline__ unsigned short f2bf(float f) {
    union { float f; unsigned u; } v; v.f = f;
    unsigned r = v.u + 0x7fffu + ((v.u >> 16) & 1u);
    return (unsigned short)(r >> 16);
}

#define AS1 __attribute__((address_space(1)))
#define AS3 __attribute__((address_space(3)))
// async 16B/lane global->LDS
__device__ __forceinline__ void async16(const void* g, void* l) {
    __builtin_amdgcn_global_load_lds((AS1 void*)g, (AS3 void*)l, 16, 0, 0);
}

// CK-style barrier: orders LDS only (lgkmcnt), leaves global loads (vmcnt) in flight.
__device__ __forceinline__ void sync_lds() {
    asm volatile("s_waitcnt lgkmcnt(0)\n\ts_barrier" ::: "memory");
}

// XOR swizzle for 32-col (4-group) rows
#define SWZ4(r) ((((r) & 3) ^ (((r) >> 2) & 3)))

// ---------------- weight transpose + bf16 convert: W[K][N] -> Wt[N][K] ----------------
__global__ void transpose_cvt(const float* __restrict__ W, unsigned short* __restrict__ Wt,
                              int K, int N) {
    __shared__ float tile[32][33];
    int n0 = blockIdx.x * 32, k0 = blockIdx.y * 32;
    int tx = threadIdx.x, ty = threadIdx.y;
#pragma unroll
    for (int i = 0; i < 32; i += 8)
        tile[ty + i][tx] = W[(size_t)(k0 + ty + i) * N + n0 + tx];
    __syncthreads();
#pragma unroll
    for (int i = 0; i < 32; i += 8)
        Wt[(size_t)(n0 + ty + i) * K + k0 + tx] = f2bf(tile[tx][ty + i]);
}

// ---------------- LayerNorm (ddof=1, /(std+eps)), fp32 in -> bf16 out ----------------
__global__ __launch_bounds__(256) void ln_kernel(const float* __restrict__ x,
                                                 unsigned short* __restrict__ t,
                                                 const float* __restrict__ alpha,
                                                 const float* __restrict__ bias) {
    const int row = blockIdx.x;
    const float* xr = x + (size_t)row * 768;
    float v[3], sum = 0.f, ss = 0.f;
#pragma unroll
    for (int i = 0; i < 3; i++) {
        v[i] = xr[threadIdx.x + 256 * i];
        sum += v[i]; ss += v[i] * v[i];
    }
#pragma unroll
    for (int off = 32; off; off >>= 1) {
        sum += __shfl_down(sum, off);
        ss  += __shfl_down(ss, off);
    }
    __shared__ float s1[4], s2[4];
    int wid = threadIdx.x >> 6, lane = threadIdx.x & 63;
    if (lane == 0) { s1[wid] = sum; s2[wid] = ss; }
    __syncthreads();
    if (threadIdx.x == 0) {
        float a = 0.f, b = 0.f;
#pragma unroll
        for (int i = 0; i < 4; i++) { a += s1[i]; b += s2[i]; }
        s1[0] = a; s2[0] = b;
    }
    __syncthreads();
    sum = s1[0]; ss = s2[0];
    float mean = sum * (1.f / 768.f);
    float var = (ss - sum * mean) * (1.f / 767.f);   // unbiased (ddof=1)
    float sc = alpha[0] / (sqrtf(fmaxf(var, 0.f)) + 1e-6f);
    float bs = bias[0];
#pragma unroll
    for (int i = 0; i < 3; i++)
        t[(size_t)row * 768 + threadIdx.x + 256 * i] = f2bf(sc * (v[i] - mean) + bs);
}

// ---------------- GEMM 128x128, register-prefetch pipelined, BK=32 --------------------
// MODE 0: out bf16 = v              MODE 1: out bf16 = relu(v + bias[col])
// MODE 2: out f32 = v + res         MODE 3: out f32 = v + bias[col] + res
template <int MODE>
__global__ __launch_bounds__(256, 3) void gemm_bt(
    const unsigned short* __restrict__ A, const unsigned short* __restrict__ Bt,
    int M, int N, int K, const float* __restrict__ bias,
    const float* __restrict__ res, void* __restrict__ outp) {
    __shared__ __align__(16) unsigned short As[2][128 * 32];
    __shared__ __align__(16) unsigned short Bs[2][128 * 32];
    const int tid = threadIdx.x;
    const int lane = tid & 63, w = tid >> 6;
    const int wm = w & 1, wn = w >> 1;
    const int m0 = blockIdx.y * 128, n0 = blockIdx.x * 128;
    const int quad = lane >> 4, l16 = lane & 15;

    const int r0 = tid >> 2, g0 = tid & 3;           // rows 0..63
    const int r1 = r0 + 64, g1 = g0;                 // rows 64..127
    const unsigned short* gA0 = A  + (size_t)(m0 + r0) * K + g0 * 8;
    const unsigned short* gA1 = A  + (size_t)(m0 + r1) * K + g1 * 8;
    const unsigned short* gB0 = Bt + (size_t)(n0 + r0) * K + g0 * 8;
    const unsigned short* gB1 = Bt + (size_t)(n0 + r1) * K + g1 * 8;
    const int wA0 = r0 * 32 + ((g0 ^ SWZ4(r0)) * 8);
    const int wA1 = r1 * 32 + ((g1 ^ SWZ4(r1)) * 8);

    f32x4 acc[4][4];
    const f32x4 z = {0.f, 0.f, 0.f, 0.f};
#pragma unroll
    for (int mt = 0; mt < 4; mt++)
#pragma unroll
        for (int nt = 0; nt < 4; nt++) acc[mt][nt] = z;

    bf16x8 ra0 = *(const bf16x8*)gA0, ra1 = *(const bf16x8*)gA1;
    bf16x8 rb0 = *(const bf16x8*)gB0, rb1 = *(const bf16x8*)gB1;
    gA0 += 32; gA1 += 32; gB0 += 32; gB1 += 32;

    const int nK = K >> 5;
    for (int kt = 0; kt < nK; ++kt) {
        unsigned short* Ac = As[kt & 1];
        unsigned short* Bc = Bs[kt & 1];
        *(bf16x8*)&Ac[wA0] = ra0; *(bf16x8*)&Ac[wA1] = ra1;
        *(bf16x8*)&Bc[wA0] = rb0; *(bf16x8*)&Bc[wA1] = rb1;
        if (kt + 1 < nK) {
            ra0 = *(const bf16x8*)gA0; ra1 = *(const bf16x8*)gA1;
            rb0 = *(const bf16x8*)gB0; rb1 = *(const bf16x8*)gB1;
            gA0 += 32; gA1 += 32; gB0 += 32; gB1 += 32;
        }
        sync_lds();
        bf16x8 af[4], bf[4];
#pragma unroll
        for (int mt = 0; mt < 4; mt++) {
            int r = 64 * wm + 16 * mt + l16;
            af[mt] = *(const bf16x8*)&Ac[r * 32 + ((quad ^ SWZ4(r)) * 8)];
        }
#pragma unroll
        for (int nt = 0; nt < 4; nt++) {
            int r = 64 * wn + 16 * nt + l16;
            bf[nt] = *(const bf16x8*)&Bc[r * 32 + ((quad ^ SWZ4(r)) * 8)];
        }
#pragma unroll
        for (int mt = 0; mt < 4; mt++)
#pragma unroll
            for (int nt = 0; nt < 4; nt++)
                acc[mt][nt] = __builtin_amdgcn_mfma_f32_16x16x32_bf16(af[mt], bf[nt], acc[mt][nt], 0, 0, 0);
    }

#pragma unroll
    for (int mt = 0; mt < 4; mt++) {
#pragma unroll
        for (int nt = 0; nt < 4; nt++) {
            const int col = n0 + 64 * wn + 16 * nt + l16;
            float bv = 0.f;
            if (MODE == 1 || MODE == 3) bv = bias[col];
#pragma unroll
            for (int r = 0; r < 4; r++) {
                const int row = m0 + 64 * wm + 16 * mt + quad * 4 + r;
                const size_t idx = (size_t)row * N + col;
                const float v = acc[mt][nt][r];
                if (MODE == 0) ((unsigned short*)outp)[idx] = f2bf(v);
                else if (MODE == 1) ((unsigned short*)outp)[idx] = f2bf(fmaxf(v + bv, 0.f));
                else if (MODE == 2) ((float*)outp)[idx] = v + res[idx];
                else ((float*)outp)[idx] = v + bv + res[idx];
            }
        }
    }
}

// ---------------- GEMM 64x64, register-prefetch pipelined, BK=64 ----------------------
template <int MODE>
__global__ __launch_bounds__(256, 3) void gemm64_bt(
    const unsigned short* __restrict__ A, const unsigned short* __restrict__ Bt,
    int M, int N, int K, const float* __restrict__ bias,
    const float* __restrict__ res, void* __restrict__ outp) {
    __shared__ __align__(16) unsigned short As[2][64 * 64];
    __shared__ __align__(16) unsigned short Bs[2][64 * 64];
    const int tid = threadIdx.x;
    const int lane = tid & 63, w = tid >> 6;
    const int m0 = blockIdx.y * 64, n0 = blockIdx.x * 64;
    const int quad = lane >> 4, l16 = lane & 15;

    const int r0 = tid >> 3, g0 = tid & 7;           // rows 0..31
    const int r1 = r0 + 32, g1 = g0;                 // rows 32..63
    const unsigned short* gA0 = A  + (size_t)(m0 + r0) * K + g0 * 8;
    const unsigned short* gA1 = A  + (size_t)(m0 + r1) * K + g1 * 8;
    const unsigned short* gB0 = Bt + (size_t)(n0 + r0) * K + g0 * 8;
    const unsigned short* gB1 = Bt + (size_t)(n0 + r1) * K + g1 * 8;
    const int wA0 = r0 * 64 + ((g0 ^ (r0 & 7)) * 8);
    const int wA1 = r1 * 64 + ((g1 ^ (r1 & 7)) * 8);

    f32x4 acc[4];
    const f32x4 z = {0.f, 0.f, 0.f, 0.f};
#pragma unroll
    for (int nt = 0; nt < 4; nt++) acc[nt] = z;

    bf16x8 ra0 = *(const bf16x8*)gA0, ra1 = *(const bf16x8*)gA1;
    bf16x8 rb0 = *(const bf16x8*)gB0, rb1 = *(const bf16x8*)gB1;
    gA0 += 64; gA1 += 64; gB0 += 64; gB1 += 64;

    const int nK = K >> 6;
    for (int kt = 0; kt < nK; ++kt) {
        unsigned short* Ac = As[kt & 1];
        unsigned short* Bc = Bs[kt & 1];
        *(bf16x8*)&Ac[wA0] = ra0; *(bf16x8*)&Ac[wA1] = ra1;
        *(bf16x8*)&Bc[wA0] = rb0; *(bf16x8*)&Bc[wA1] = rb1;
        if (kt + 1 < nK) {
            ra0 = *(const bf16x8*)gA0; ra1 = *(const bf16x8*)gA1;
            rb0 = *(const bf16x8*)gB0; rb1 = *(const bf16x8*)gB1;
            gA0 += 64; gA1 += 64; gB0 += 64; gB1 += 64;
        }
        sync_lds();
        const int ra = 16 * w + l16;
        bf16x8 af0 = *(const bf16x8*)&Ac[ra * 64 + (((0 + quad) ^ (ra & 7)) * 8)];
        bf16x8 af1 = *(const bf16x8*)&Ac[ra * 64 + (((4 + quad) ^ (ra & 7)) * 8)];
#pragma unroll
        for (int nt = 0; nt < 4; nt++) {
            int rb = 16 * nt + l16;
            bf16x8 bf0 = *(const bf16x8*)&Bc[rb * 64 + (((0 + quad) ^ (rb & 7)) * 8)];
            bf16x8 bf1 = *(const bf16x8*)&Bc[rb * 64 + (((4 + quad) ^ (rb & 7)) * 8)];
            acc[nt] = __builtin_amdgcn_mfma_f32_16x16x32_bf16(af0, bf0, acc[nt], 0, 0, 0);
            acc[nt] = __builtin_amdgcn_mfma_f32_16x16x32_bf16(af1, bf1, acc[nt], 0, 0, 0);
        }
    }

#pragma unroll
    for (int nt = 0; nt < 4; nt++) {
        const int col = n0 + 16 * nt + l16;
        float bv = 0.f;
        if (MODE == 1 || MODE == 3) bv = bias[col];
#pragma unroll
        for (int rr = 0; rr < 4; rr++) {
            const int row = m0 + 16 * w + quad * 4 + rr;
            const size_t idx = (size_t)row * N + col;
            const float v = acc[nt][rr];
            if (MODE == 0) ((unsigned short*)outp)[idx] = f2bf(v);
            else if (MODE == 1) ((unsigned short*)outp)[idx] = f2bf(fmaxf(v + bv, 0.f));
            else if (MODE == 2) ((float*)outp)[idx] = v + res[idx];
            else ((float*)outp)[idx] = v + bv + res[idx];
        }
    }
}

// ---------------- V transpose: qkv[.,1536+h*64+dd] -> vt[bh][dd][S] ----------------
__global__ void v_transpose(const unsigned short* __restrict__ qkvc,
                            unsigned short* __restrict__ vt) {
    __shared__ unsigned short t[64][65];
    const int bh = blockIdx.y, b = bh / 12, h = bh % 12;
    const int s0 = blockIdx.x * 64;
    const int tx = threadIdx.x, ty = threadIdx.y;   // 64 x 4
#pragma unroll
    for (int i = 0; i < 64; i += 4)
        t[ty + i][tx] = qkvc[(size_t)(b * 2048 + s0 + ty + i) * 2304 + 1536 + h * 64 + tx];
    __syncthreads();
#pragma unroll
    for (int i = 0; i < 64; i += 4)
        vt[((size_t)bh * 64 + ty + i) * 2048 + s0 + tx] = t[tx][ty + i];
}

// ---------------- flash attention v9: 2x2 hybrid + S^T with cheap VALU path -----------
// v8's S^T orientation (one ds_write_b64 per 16x16 tile instead of 4 scalar b16) but
// with v7's cheap per-element math: select on the INPUT (1 cndmask) -> exp2 -> hardware
// (__bf16) cast, no manual f2bf rounding (v8's VALU 52% regression). The b64 write's
// ~4 conflicts/instr is the inherent 128-word/32-bank floor — still fewer LDS cycles
// than 32 scalar writes.
__global__ __launch_bounds__(256, 3) void flash_attn(
    const unsigned short* __restrict__ qkvc,   // [4096][2304] fused q|k|v
    const unsigned short* __restrict__ vt,     // [24][64][2048]
    const int* __restrict__ mask,              // [2][2048]
    unsigned short* __restrict__ attno) {      // [4096][768]
    const int bh = blockIdx.y, b = bh / 12, h = bh % 12;
    const int s0 = blockIdx.x * 64;
    __shared__ __align__(16) unsigned short UQP[4 * 32 * 72];  // Qs pre-loop; Ps[w][32][72]
    __shared__ __align__(16) unsigned short Ks[128 * 64];      // fp32 Osc[64][64] in epilogue
    __shared__ __align__(16) unsigned short Vs[64 * 128];      // fp32 Lsc[64] in epilogue
    __shared__ int Ms[128];
    const int tid = threadIdx.x, lane = tid & 63, w = tid >> 6;
    const int quad = lane >> 4, l16 = lane & 15;
    const int wq = w & 1, wk = w >> 1;

    // stage Q tile [64 rows][64 cols] (swizzle g^(r&7)) via async16, once
    {
        int sl0 = (2 * w) * 64 + lane;
        int r0 = sl0 >> 3, g0 = sl0 & 7;
        int sl1 = sl0 + 64;
        int r1 = sl1 >> 3, g1 = sl1 & 7;
        async16(qkvc + (size_t)(b * 2048 + s0 + r0) * 2304 + h * 64 + ((g0 ^ (r0 & 7)) * 8),
                UQP + (2 * w) * 512);
        async16(qkvc + (size_t)(b * 2048 + s0 + r1) * 2304 + h * 64 + ((g1 ^ (r1 & 7)) * 8),
                UQP + (2 * w + 1) * 512);
    }
    __syncthreads();
    // Q frags for this wave's 32 q-rows; used as B-operand (layout bit-identical)
    bf16x8 aQ[2][2];
#pragma unroll
    for (int mt = 0; mt < 2; mt++) {
        int r = wq * 32 + mt * 16 + l16;
#pragma unroll
        for (int kk = 0; kk < 2; kk++)
            aQ[mt][kk] = *(const bf16x8*)&UQP[r * 64 + (((kk * 4 + quad) ^ (r & 7)) * 8)];
    }
    __syncthreads();   // all waves done reading Q before Ps overwrites the region
    __bf16* Ps = (__bf16*)UQP + w * (32 * 72);   // wave-local [32 q][stride 72]

    f32x4 Oacc[2][4], Lacc[2];
    const f32x4 z = {0.f, 0.f, 0.f, 0.f};
#pragma unroll
    for (int mt = 0; mt < 2; mt++) {
        Lacc[mt] = z;
#pragma unroll
        for (int nt = 0; nt < 4; nt++) Oacc[mt][nt] = z;
    }
    bf16x8 ones;
#pragma unroll
    for (int i = 0; i < 8; i++) ones[i] = (__bf16)1.0f;

    const unsigned short* kbase = qkvc + 768;
    const unsigned short* vbase = vt + (size_t)bh * 64 * 2048;
    const float SCL = 0.125f * 1.44269504088896340736f;   // 1/sqrt(64) * log2(e)
    const float MSK = 1.4426950408889634e-9f;             // 1e-9 * log2(e)

    for (int j = 0; j < 16; j++) {
        const int k0 = j * 128;
        __syncthreads();
        // stage K tile [128][64] (swizzle g^(r&7)) and V^T tile [64][128] (g^(r&15))
#pragma unroll
        for (int c = 0; c < 4; c++) {
            int sl = (4 * w + c) * 64 + lane;
            int r = sl >> 3, g = sl & 7;
            async16(kbase + (size_t)(b * 2048 + k0 + r) * 2304 + h * 64 + ((g ^ (r & 7)) * 8),
                    Ks + (4 * w + c) * 512);
        }
#pragma unroll
        for (int c = 0; c < 4; c++) {
            int sl = (4 * w + c) * 64 + lane;
            int r = sl >> 4, g = sl & 15;
            async16(vbase + (size_t)r * 2048 + k0 + ((g ^ (r & 15)) * 8),
                    Vs + (4 * w + c) * 512);
        }
        if (tid < 128) Ms[tid] = mask[b * 2048 + k0 + tid];
        __syncthreads();

        // S^T[64 k][32 q] for this wave's quadrant: mfma(A=K, B=Q). C-layout: lane
        // l16 = q, rows quad*4+r = 4 consecutive k -> one b64 P-write per tile.
#pragma unroll
        for (int nt = 0; nt < 4; nt++) {
            const int rr = wk * 64 + nt * 16 + l16;
            bf16x8 bk0 = *(const bf16x8*)&Ks[rr * 64 + (((0 + quad) ^ (rr & 7)) * 8)];
            bf16x8 bk1 = *(const bf16x8*)&Ks[rr * 64 + (((4 + quad) ^ (rr & 7)) * 8)];
            const i32x4 mk4 = *(const i32x4*)&Ms[wk * 64 + nt * 16 + quad * 4];
#pragma unroll
            for (int mt = 0; mt < 2; mt++) {
                f32x4 t0 = __builtin_amdgcn_mfma_f32_16x16x32_bf16(bk0, aQ[mt][0], z, 0, 0, 0);
                f32x4 sc = __builtin_amdgcn_mfma_f32_16x16x32_bf16(bk1, aQ[mt][1], t0, 0, 0, 0);
                union { unsigned long long u64; __bf16 bb[4]; } pk;
#pragma unroll
                for (int r = 0; r < 4; r++) {
                    const float v = mk4[r] ? sc[r] * SCL : MSK;   // 1 mul + 1 cndmask
                    pk.bb[r] = (__bf16)__builtin_amdgcn_exp2f(v); // hw cvt
                }
                *(unsigned long long*)&Ps[(mt * 16 + l16) * 72 + nt * 16 + quad * 4] = pk.u64;
            }
        }

        // O_w += P_w V[64k chunk] ; L_w += P_w 1
#pragma unroll
        for (int kt2 = 0; kt2 < 2; kt2++) {
#pragma unroll
            for (int mt = 0; mt < 2; mt++) {
                bf16x8 aP = *(const bf16x8*)&Ps[(mt * 16 + l16) * 72 + kt2 * 32 + quad * 8];
                Lacc[mt] = __builtin_amdgcn_mfma_f32_16x16x32_bf16(aP, ones, Lacc[mt], 0, 0, 0);
#pragma unroll
                for (int nt = 0; nt < 4; nt++) {
                    const int rr = nt * 16 + l16;
                    bf16x8 bv = *(const bf16x8*)&Vs[rr * 128 +
                                (((wk * 8 + kt2 * 4 + quad) ^ (rr & 15)) * 8)];
                    Oacc[mt][nt] = __builtin_amdgcn_mfma_f32_16x16x32_bf16(aP, bv, Oacc[mt][nt], 0, 0, 0);
                }
            }
        }
    }

    // ---- pair-merge: wk=1 publishes partials, wk=0 adds + stores ----
    __syncthreads();
    float* Osc = (float*)Ks;   // [64 q][64 d] fp32 = 16KB
    float* Lsc = (float*)Vs;   // [64 q] fp32
    if (wk == 1) {
#pragma unroll
        for (int mt = 0; mt < 2; mt++) {
            if (l16 == 0)
#pragma unroll
                for (int r = 0; r < 4; r++)
                    Lsc[wq * 32 + mt * 16 + quad * 4 + r] = Lacc[mt][r];
#pragma unroll
            for (int nt = 0; nt < 4; nt++)
#pragma unroll
                for (int r = 0; r < 4; r++)
                    Osc[(size_t)(wq * 32 + mt * 16 + quad * 4 + r) * 64 + nt * 16 + l16] =
                        Oacc[mt][nt][r];
        }
    }
    __syncthreads();
    if (wk == 0) {
#pragma unroll
        for (int mt = 0; mt < 2; mt++) {
#pragma unroll
            for (int r = 0; r < 4; r++) {
                const int ql = wq * 32 + mt * 16 + quad * 4 + r;
                const float L = Lacc[mt][r] + Lsc[ql];
                const float inv = 1.0f / L;
                const int row = s0 + ql;
#pragma unroll
                for (int nt = 0; nt < 4; nt++) {
                    const float s = Oacc[mt][nt][r] + Osc[(size_t)ql * 64 + nt * 16 + l16];
                    attno[(size_t)(b * 2048 + row) * 768 + h * 64 + nt * 16 + l16] =
                        f2bf(s * inv);
                }
            }
        }
    }
}

// =====================================================================================
extern "C" void kernel_launch(void* const* d_in, const int* in_sizes, int n_in,
                              void* d_out, int out_size, void* d_ws, size_t ws_size,
                              hipStream_t stream) {
    const float* x    = (const float*)d_in[0];
    const int*   mask = (const int*)d_in[1];
    const float* wq   = (const float*)d_in[2];
    const float* wk   = (const float*)d_in[3];
    const float* wv   = (const float*)d_in[4];
    const float* wo   = (const float*)d_in[5];
    const float* w1   = (const float*)d_in[6];
    const float* b1   = (const float*)d_in[7];
    const float* w2   = (const float*)d_in[8];
    const float* b2   = (const float*)d_in[9];
    const float* ln1a = (const float*)d_in[10];
    const float* ln1b = (const float*)d_in[11];
    const float* ln2a = (const float*)d_in[12];
    const float* ln2b = (const float*)d_in[13];

    char* p = (char*)d_ws;
    auto carve = [&](size_t bytes) {
        char* q = p;
        p += (bytes + 255) & ~(size_t)255;
        return q;
    };
    unsigned short* wTqkv = (unsigned short*)carve((size_t)2304 * 768 * 2);
    unsigned short* wTo   = (unsigned short*)carve((size_t)768 * 768 * 2);
    unsigned short* wT1   = (unsigned short*)carve((size_t)3072 * 768 * 2);
    unsigned short* wT2   = (unsigned short*)carve((size_t)768 * 3072 * 2);
    unsigned short* vtb   = (unsigned short*)carve((size_t)24 * 64 * 2048 * 2);
    float*          x1    = (float*)carve((size_t)4096 * 768 * 4);
    char* unionA = carve((size_t)4096 * 768 * 2 + (size_t)4096 * 2304 * 2);
    unsigned short* t1   = (unsigned short*)unionA;
    unsigned short* qkvc = (unsigned short*)(unionA + (size_t)4096 * 768 * 2);
    unsigned short* ffnh = (unsigned short*)unionA;
    unsigned short* attno = (unsigned short*)carve((size_t)4096 * 768 * 2);
    unsigned short* t2 = attno;

    dim3 tb(32, 8);
    transpose_cvt<<<dim3(24, 24), tb, 0, stream>>>(wq, wTqkv, 768, 768);
    transpose_cvt<<<dim3(24, 24), tb, 0, stream>>>(wk, wTqkv + (size_t)768 * 768, 768, 768);
    transpose_cvt<<<dim3(24, 24), tb, 0, stream>>>(wv, wTqkv + (size_t)1536 * 768, 768, 768);
    transpose_cvt<<<dim3(24, 24), tb, 0, stream>>>(wo, wTo, 768, 768);
    transpose_cvt<<<dim3(96, 24), tb, 0, stream>>>(w1, wT1, 768, 3072);
    transpose_cvt<<<dim3(24, 96), tb, 0, stream>>>(w2, wT2, 3072, 768);

    ln_kernel<<<4096, 256, 0, stream>>>(x, t1, ln1a, ln1b);
    gemm_bt<0><<<dim3(18, 32), 256, 0, stream>>>(t1, wTqkv, 4096, 2304, 768,
                                                 nullptr, nullptr, qkvc);
    v_transpose<<<dim3(32, 24), dim3(64, 4), 0, stream>>>(qkvc, vtb);
    flash_attn<<<dim3(32, 24), 256, 0, stream>>>(qkvc, vtb, mask, attno);
    gemm64_bt<2><<<dim3(12, 64), 256, 0, stream>>>(attno, wTo, 4096, 768, 768,
                                                   nullptr, x, x1);
    ln_kernel<<<4096, 256, 0, stream>>>(x1, t2, ln2a, ln2b);
    gemm_bt<1><<<dim3(24, 32), 256, 0, stream>>>(t2, wT1, 4096, 3072, 768,
                                                 b1, nullptr, ffnh);
    gemm64_bt<3><<<dim3(12, 64), 256, 0, stream>>>(ffnh, wT2, 4096, 768, 3072,
                                                   b2, x1, (float*)d_out);
}